// Round 2
// baseline (22668.602 us; speedup 1.0000x reference)
//
#include <hip/hip_runtime.h>
#include <stdint.h>
#include <math.h>

#define HH   512
#define BB   64
#define TT   2000
#define NEXC 409   // int(0.8 * 512)

#define NBLK   64   // total blocks: 8 clusters x 8 blocks
#define CLB    8    // blocks per cluster (each owns 64 cols)
#define NBATCH 8    // batches per cluster
#define NCOL   64   // output columns per block
#define PJ     68   // LDS pitch (floats) of wt_s[i][j]   (2-way max aliasing)
#define PR     516  // LDS pitch of rh rows               (disjoint 4-bank windows)
#define PP     520  // LDS pitch of partial rows

// Python-float constants, rounded to f32 exactly as the reference does.
constexpr float ALPHA_F     = 0.1f;
constexpr float IN_SCALE_F  = (float)4.4721359549995794e-03;
constexpr float REC_SCALE_F = (float)4.4721359549995794e-02;
constexpr float SQRT2_F     = 1.41421356237309515f;
constexpr float U_LO        = -0x1.fffffep-1f;   // nextafter(-1, 0)

struct U2 { uint32_t a, b; };

__host__ __device__ constexpr uint32_t rotl32(uint32_t x, int d) {
  return (x << d) | (x >> (32 - d));
}

// JAX Threefry-2x32, 20 rounds.
__host__ __device__ constexpr U2 tf2x32(uint32_t k0, uint32_t k1,
                                        uint32_t x0, uint32_t x1) {
  uint32_t ks[3] = {k0, k1, k0 ^ k1 ^ 0x1BD11BDAu};
  const int R[2][4] = {{13, 15, 26, 6}, {17, 29, 16, 24}};
  x0 += ks[0]; x1 += ks[1];
  for (int g = 0; g < 5; ++g) {
    const int* r = R[g & 1];
    for (int i = 0; i < 4; ++i) { x0 += x1; x1 = rotl32(x1, r[i]); x1 ^= x0; }
    x0 += ks[(g + 1) % 3];
    x1 += ks[(g + 2) % 3] + (uint32_t)(g + 1);
  }
  return U2{x0, x1};
}

constexpr U2 KIN_  = tf2x32(0u, 42u, 0u, 0u);
constexpr U2 KREC_ = tf2x32(0u, 42u, 0u, 1u);
constexpr uint32_t KIN0 = KIN_.a,  KIN1 = KIN_.b;
constexpr uint32_t KRC0 = KREC_.a, KRC1 = KREC_.b;

__device__ __forceinline__ float jax_normal(uint32_t k0, uint32_t k1, uint32_t idx) {
  U2 o = tf2x32(k0, k1, 0u, idx);
  uint32_t bits = o.a ^ o.b;
  float f = __uint_as_float((bits >> 9) | 0x3f800000u) - 1.0f;
  float u = fmaxf(U_LO, f * 2.0f + U_LO);
  float w = -log1pf(-u * u);
  float p;
  if (w < 5.0f) {
    w = w - 2.5f;
    p =             2.81022636e-08f;
    p = fmaf(p, w,  3.43273939e-07f);
    p = fmaf(p, w, -3.5233877e-06f);
    p = fmaf(p, w, -4.39150654e-06f);
    p = fmaf(p, w,  0.00021858087f);
    p = fmaf(p, w, -0.00125372503f);
    p = fmaf(p, w, -0.00417768164f);
    p = fmaf(p, w,  0.246640727f);
    p = fmaf(p, w,  1.50140941f);
  } else {
    w = sqrtf(w) - 3.0f;
    p =            -0.000200214257f;
    p = fmaf(p, w,  0.000100950558f);
    p = fmaf(p, w,  0.00134934322f);
    p = fmaf(p, w, -0.00367342844f);
    p = fmaf(p, w,  0.00573950773f);
    p = fmaf(p, w, -0.0076224613f);
    p = fmaf(p, w,  0.00943887047f);
    p = fmaf(p, w,  1.00167406f);
    p = fmaf(p, w,  2.83297682f);
  }
  return SQRT2_F * (p * u);
}

__device__ __forceinline__ float4 fma4(float a, float4 b, float4 c) {
  c.x = fmaf(a, b.x, c.x); c.y = fmaf(a, b.y, c.y);
  c.z = fmaf(a, b.z, c.z); c.w = fmaf(a, b.w, c.w);
  return c;
}

// wtg[i*H + j] = w_hh_ei[j][i] = |w_hh[j,i]| * (i!=j) * ei[i]
__global__ void prep_wt(const float* __restrict__ whh, float* __restrict__ wt) {
  int idx = blockIdx.x * blockDim.x + threadIdx.x;
  int i = idx >> 9;
  int j = idx & (HH - 1);
  float v = (i == j) ? 0.0f : fabsf(whh[j * HH + i]);
  wt[idx] = (i < NEXC) ? v : -v;
}

__global__ __launch_bounds__(512, 1)
void zrnn_main(const float* __restrict__ i_stim, const float* __restrict__ i_cc,
               const float* __restrict__ hidden0, const float* __restrict__ w_ih,
               const float* __restrict__ b_hh, const float* __restrict__ w_ho,
               const float* __restrict__ b_ho, const float* __restrict__ wtg,
               float* __restrict__ rbuf, int* __restrict__ flags,
               float* __restrict__ outs, float* __restrict__ hids) {
  const int tid = threadIdx.x;
  const int blk = blockIdx.x;
  const int c = blk >> 3;   // cluster
  const int k = blk & 7;    // block-in-cluster (owns cols [64k,64k+64), out-batch 8c+k)

  __shared__ __align__(16) float wt_s[HH * PJ];       // 139264 B, time-invariant
  __shared__ __align__(16) float rhp[NBATCH * PP];    // 16640 B: rh (pitch PR) / partials (pitch PP)
  __shared__ float cur_s[NBATCH * 2];
  __shared__ float red[8];

  // update-role indices
  const int lb = tid >> 6;               // local batch
  const int lj = tid & 63;               // local col
  const int bg = c * NBATCH + lb;        // global batch
  const int jg = k * NCOL + lj;          // global col
  // matvec tile-role indices: 16 i-slices x (2 bq x 16 jq) 4x4 tiles
  const int s  = tid >> 5;
  const int bq = (tid >> 4) & 1;
  const int jq = tid & 15;
  const int i0 = s * 32;

  float h = hidden0[bg * HH + jg];
  const float wih0 = w_ih[jg * 2 + 0];
  const float wih1 = w_ih[jg * 2 + 1];
  const float bhh  = b_hh[jg];
  const float who  = w_ho[tid];          // used as w_ho[i] in the out-reduction
  const float bho  = b_ho[0];
  const int bown = c * NBATCH + k;

  // Fill wt_s[i][lj] = wtg[i][64k+lj] (coalesced float4, one-time)
  #pragma unroll
  for (int rr = 0; rr < 16; ++rr) {
    int q = rr * 512 + tid;
    int i = q >> 4, c4 = q & 15;
    float4 v = *(const float4*)&wtg[i * HH + k * NCOL + c4 * 4];
    *(float4*)&wt_s[i * PJ + c4 * 4] = v;
  }

  // Initial publish p=0: relu(h0) -> rbuf[0]
  __hip_atomic_store(&rbuf[bg * HH + jg], fmaxf(h, 0.0f),
                     __ATOMIC_RELAXED, __HIP_MEMORY_SCOPE_AGENT);
  __syncthreads();  // drains vmcnt for all waves; also covers wt_s fill
  if (tid == 0)
    __hip_atomic_store(&flags[blk * 32], 1, __ATOMIC_RELEASE, __HIP_MEMORY_SCOPE_AGENT);

  for (int t = 0; t <= TT; ++t) {
    // ---- poll: need all cluster publishes p=t (flag >= t+1) ----
    if (tid < CLB) {
      int* fp = &flags[(c * CLB + tid) * 32];
      while (__hip_atomic_load(fp, __ATOMIC_ACQUIRE, __HIP_MEMORY_SCOPE_AGENT) < t + 1)
        __builtin_amdgcn_s_sleep(1);
    }
    __syncthreads();

    // ---- fetch p=t (relu(h(t)) for 8 cluster batches) into rhp ----
    {
      const float* src = rbuf + (size_t)(t & 1) * (BB * HH) + (size_t)c * NBATCH * HH;
      float vf[8];
      #pragma unroll
      for (int rr = 0; rr < 8; ++rr)
        vf[rr] = __hip_atomic_load(&src[rr * HH + tid],
                                   __ATOMIC_RELAXED, __HIP_MEMORY_SCOPE_AGENT);
      #pragma unroll
      for (int rr = 0; rr < 8; ++rr)
        rhp[rr * PR + tid] = vf[rr];
    }
    __syncthreads();

    // ---- out(t-1) for own batch: sum_i rh[k][i]*w_ho[i] (shuffle + red[]) ----
    if (t >= 1) {
      float ov = rhp[k * PR + tid] * who;
      #pragma unroll
      for (int off = 32; off > 0; off >>= 1) ov += __shfl_down(ov, off);
      if ((tid & 63) == 0) red[tid >> 6] = ov;
    }
    if (t == TT) {
      __syncthreads();
      if (tid == 0) {
        float ssum = ((red[0] + red[1]) + (red[2] + red[3])) +
                     ((red[4] + red[5]) + (red[6] + red[7]));
        outs[bown * TT + (TT - 1)] = ssum + bho;
      }
      break;
    }

    // ---- input currents for the 8 cluster batches ----
    if (tid < NBATCH) {
      int bgl = c * NBATCH + tid;
      float st  = i_stim[bgl * TT + t];
      float cc2 = i_cc[bgl * TT + t];
      uint32_t nb = (uint32_t)t * (BB * 2) + (uint32_t)bgl * 2;
      float n0 = jax_normal(KIN0, KIN1, nb);
      float n1 = jax_normal(KIN0, KIN1, nb + 1);
      cur_s[tid * 2 + 0] = fmaxf(st  + IN_SCALE_F * n0, 0.0f);
      cur_s[tid * 2 + 1] = fmaxf(cc2 + IN_SCALE_F * n1, 0.0f);
    }

    // ---- matvec: 4 batches x 4 cols register tile over 32-i slice ----
    float4 a0 = {0,0,0,0}, a1 = {0,0,0,0}, a2 = {0,0,0,0}, a3 = {0,0,0,0};
    #pragma unroll
    for (int g = 0; g < 8; ++g) {
      int i = i0 + g * 4;
      float4 w0 = *(const float4*)&wt_s[(i + 0) * PJ + jq * 4];
      float4 w1 = *(const float4*)&wt_s[(i + 1) * PJ + jq * 4];
      float4 w2 = *(const float4*)&wt_s[(i + 2) * PJ + jq * 4];
      float4 w3 = *(const float4*)&wt_s[(i + 3) * PJ + jq * 4];
      float4 r0 = *(const float4*)&rhp[(bq * 4 + 0) * PR + i];
      float4 r1 = *(const float4*)&rhp[(bq * 4 + 1) * PR + i];
      float4 r2 = *(const float4*)&rhp[(bq * 4 + 2) * PR + i];
      float4 r3 = *(const float4*)&rhp[(bq * 4 + 3) * PR + i];
      a0 = fma4(r0.x, w0, a0); a0 = fma4(r0.y, w1, a0);
      a0 = fma4(r0.z, w2, a0); a0 = fma4(r0.w, w3, a0);
      a1 = fma4(r1.x, w0, a1); a1 = fma4(r1.y, w1, a1);
      a1 = fma4(r1.z, w2, a1); a1 = fma4(r1.w, w3, a1);
      a2 = fma4(r2.x, w0, a2); a2 = fma4(r2.y, w1, a2);
      a2 = fma4(r2.z, w2, a2); a2 = fma4(r2.w, w3, a2);
      a3 = fma4(r3.x, w0, a3); a3 = fma4(r3.y, w1, a3);
      a3 = fma4(r3.z, w2, a3); a3 = fma4(r3.w, w3, a3);
    }
    __syncthreads();   // rh reads done -> partials may overlay rhp

    if (t >= 1 && tid == 0) {
      float ssum = ((red[0] + red[1]) + (red[2] + red[3])) +
                   ((red[4] + red[5]) + (red[6] + red[7]));
      outs[bown * TT + (t - 1)] = ssum + bho;
    }

    // ---- partial reduction: phase 1 (s<8 writes), phase 2 (s>=8 adds) ----
    if (s < 8) {
      *(float4*)&rhp[s * PP + (bq * 4 + 0) * 64 + jq * 4] = a0;
      *(float4*)&rhp[s * PP + (bq * 4 + 1) * 64 + jq * 4] = a1;
      *(float4*)&rhp[s * PP + (bq * 4 + 2) * 64 + jq * 4] = a2;
      *(float4*)&rhp[s * PP + (bq * 4 + 3) * 64 + jq * 4] = a3;
    }
    __syncthreads();
    if (s >= 8) {
      int s2 = s - 8;
      float4* p0 = (float4*)&rhp[s2 * PP + (bq * 4 + 0) * 64 + jq * 4];
      float4* p1 = (float4*)&rhp[s2 * PP + (bq * 4 + 1) * 64 + jq * 4];
      float4* p2 = (float4*)&rhp[s2 * PP + (bq * 4 + 2) * 64 + jq * 4];
      float4* p3 = (float4*)&rhp[s2 * PP + (bq * 4 + 3) * 64 + jq * 4];
      float4 v0 = *p0, v1 = *p1, v2 = *p2, v3 = *p3;
      v0.x += a0.x; v0.y += a0.y; v0.z += a0.z; v0.w += a0.w;
      v1.x += a1.x; v1.y += a1.y; v1.z += a1.z; v1.w += a1.w;
      v2.x += a2.x; v2.y += a2.y; v2.z += a2.z; v2.w += a2.w;
      v3.x += a3.x; v3.y += a3.y; v3.z += a3.z; v3.w += a3.w;
      *p0 = v0; *p1 = v1; *p2 = v2; *p3 = v3;
    }
    __syncthreads();

    // ---- final: thread (lb,lj) sums 8 partials, updates h, publishes ----
    float dot = 0.0f;
    #pragma unroll
    for (int s2 = 0; s2 < 8; ++s2) dot += rhp[s2 * PP + lb * 64 + lj];

    uint32_t ridx = (uint32_t)t * (uint32_t)(BB * HH) + (uint32_t)(bg * HH + jg);
    float nr = jax_normal(KRC0, KRC1, ridx);
    float hid_hid = dot + bhh + REC_SCALE_F * nr;
    float hid_in  = cur_s[lb * 2 + 0] * wih0 + cur_s[lb * 2 + 1] * wih1;
    h = h + (-h + hid_in + hid_hid) * ALPHA_F;

    __builtin_nontemporal_store(h, &hids[((size_t)bg * TT + t) * HH + jg]);
    __hip_atomic_store(&rbuf[(size_t)((t + 1) & 1) * (BB * HH) + bg * HH + jg],
                       fmaxf(h, 0.0f), __ATOMIC_RELAXED, __HIP_MEMORY_SCOPE_AGENT);
    __syncthreads();   // all waves drain vmcnt before flag
    if (tid == 0)
      __hip_atomic_store(&flags[blk * 32], t + 2,
                         __ATOMIC_RELEASE, __HIP_MEMORY_SCOPE_AGENT);
  }
}

extern "C" void kernel_launch(void* const* d_in, const int* in_sizes, int n_in,
                              void* d_out, int out_size, void* d_ws, size_t ws_size,
                              hipStream_t stream) {
  const float* i_stim = (const float*)d_in[0];
  const float* i_cc   = (const float*)d_in[1];
  const float* hidden = (const float*)d_in[2];
  const float* w_ih   = (const float*)d_in[3];
  // d_in[4] = b_ih — never used by the reference
  const float* w_hh   = (const float*)d_in[5];
  const float* b_hh   = (const float*)d_in[6];
  const float* w_ho   = (const float*)d_in[7];
  const float* b_ho   = (const float*)d_in[8];

  float* outs = (float*)d_out;
  float* hids = (float*)d_out + (size_t)BB * TT;

  float* wtg  = (float*)d_ws;                     // 512*512 f32 = 1 MB
  float* rbuf = wtg + HH * HH;                    // 2*64*512 f32 = 256 KB
  int*   flags = (int*)(rbuf + 2 * BB * HH);      // 64 flags, 128B apart = 8 KB

  hipMemsetAsync(flags, 0, NBLK * 32 * sizeof(int), stream);
  prep_wt<<<(HH * HH) / 256, 256, 0, stream>>>(w_hh, wtg);
  zrnn_main<<<NBLK, 512, 0, stream>>>(i_stim, i_cc, hidden, w_ih, b_hh,
                                      w_ho, b_ho, wtg, rbuf, flags, outs, hids);
}